// Round 10
// baseline (2146.346 us; speedup 1.0000x reference)
//
#include <hip/hip_runtime.h>
#include <cmath>

// ---------------- workspace layout (float offsets) ----------------
constexpr long XN_OFF   = 0;          // 16*1*64^3          = 4194304
constexpr long Y0_OFF   = 4194304;    // 16*20*32^3         = 10485760
constexpr long Y1_OFF   = 14680064;   // 16*20*16^3         = 1310720
constexpr long Y2_OFF   = 15990784;   // 16*28*8^3          = 229376
constexpr long Y3_OFF   = 16220160;   // 16*64*4^3          = 65536
// padded weight layout: [co][ci][49][8] (tap row padded 7->8 for float4 s_loads)
constexpr long K0_OFF   = 16285696;   // 20*1*392   = 7840
constexpr long K1_OFF   = 16293536;   // 20*56*392  = 439040
constexpr long K2_OFF   = 16732576;   // 28*56*392  = 614656
constexpr long K3_OFF   = 17347232;   // 64*64*392  = 1605632
constexpr long BAS_OFF  = 18952864;   // 272685 gaussians
constexpr long SCR_OFF  = 19225552;   // MT scratch (uint32), ~957k words
// double-precision regions (float offsets even for 8B alignment)
constexpr long PARTD_OFF = 20182872;  // 4096 doubles
constexpr long SSD_OFF   = 20191064;  // 128 doubles
constexpr long ISTD_OFF  = 20191320;  // 2 doubles
constexpr long POOLD_OFF = 20191324;  // 1024 doubles
constexpr long CNT_OFF   = 20193372;  // 272 ints (polar group counts)
constexpr long GBASE_OFF = 20193644;  // 272 ints (polar group bases)

constexpr int PGRP = 4096;  // candidate pairs per polar group
constexpr int MAXG = 16;    // max groups per generator

struct GenDesc {
  double sdiv[17];
  int seed[17], n[17], scr_off[17], L[17], basis_off[17];
};
struct AsmDesc {
  const float* w[17];
  int cum[18];
  int basis_off[17], row_off[17], col_off[17];
  int dd[17], di[17], mi[17], nb[17], citot[17];
  long koff[17];
};

// ---------------- MT19937 fill (parallel 3-stage twist) ----------------
__global__ __launch_bounds__(256)
void mt_fill_kernel(unsigned int* __restrict__ scratch, GenDesc d) {
  __shared__ unsigned int mt[624];
  const int bb = blockIdx.x;
  const int tid = threadIdx.x;
  if (tid == 0) {
    unsigned int s = (unsigned int)d.seed[bb];
    for (int pos = 0; pos < 624; pos++) {
      mt[pos] = s;
      s = 1812433253u * (s ^ (s >> 30)) + (unsigned)pos + 1u;
    }
  }
  __syncthreads();
  unsigned int* out = scratch + d.scr_off[bb];
  const int L = d.L[bb];
  const int ntw = (L + 623) / 624;
  for (int t = 0; t < ntw; t++) {
    unsigned int v1 = 0, v2 = 0;
    if (tid < 227) { v1 = mt[tid]; v2 = mt[tid + 1]; }
    __syncthreads();
    if (tid < 227) {
      unsigned int y = (v1 & 0x80000000u) | (v2 & 0x7fffffffu);
      mt[tid] = mt[tid + 397] ^ (y >> 1) ^ ((y & 1u) ? 0x9908b0dfu : 0u);
    }
    __syncthreads();
    if (tid < 227) { v1 = mt[227 + tid]; v2 = mt[228 + tid]; }
    __syncthreads();
    if (tid < 227) {
      unsigned int y = (v1 & 0x80000000u) | (v2 & 0x7fffffffu);
      mt[227 + tid] = mt[tid] ^ (y >> 1) ^ ((y & 1u) ? 0x9908b0dfu : 0u);
    }
    __syncthreads();
    if (tid < 170) {
      int i = 454 + tid;
      v1 = mt[i]; v2 = (i < 623) ? mt[i + 1] : mt[0];
    }
    __syncthreads();
    if (tid < 170) {
      int i = 454 + tid;
      unsigned int y = (v1 & 0x80000000u) | (v2 & 0x7fffffffu);
      mt[i] = mt[i - 227] ^ (y >> 1) ^ ((y & 1u) ? 0x9908b0dfu : 0u);
    }
    __syncthreads();
    const int base = t * 624;
    for (int j = tid; j < 624; j += 256) {
      if (base + j < L) {
        unsigned int y = mt[j];
        y ^= y >> 11;
        y ^= (y << 7) & 0x9d2c5680u;
        y ^= (y << 15) & 0xefc60000u;
        y ^= y >> 18;
        out[base + j] = y;
      }
    }
    __syncthreads();
  }
}

// ---------------- polar: count -> scan -> write (bit-exact numpy stream) ----------------
__device__ inline bool polar_accept(const unsigned int* src, int p,
                                    double& x1, double& x2, double& r2) {
  unsigned int w0 = src[4 * p], w1 = src[4 * p + 1], w2 = src[4 * p + 2], w3 = src[4 * p + 3];
  double u1 = ((double)(w0 >> 5) * 67108864.0 + (double)(w1 >> 6)) * (1.0 / 9007199254740992.0);
  double u2 = ((double)(w2 >> 5) * 67108864.0 + (double)(w3 >> 6)) * (1.0 / 9007199254740992.0);
  x1 = 2.0 * u1 - 1.0; x2 = 2.0 * u2 - 1.0;
  r2 = x1 * x1 + x2 * x2;
  return (r2 < 1.0) && (r2 != 0.0);
}

__global__ __launch_bounds__(256)
void polar_count_kernel(const unsigned int* __restrict__ scratch, int* __restrict__ counts,
                        GenDesc d) {
  const int bb = blockIdx.y, grp = blockIdx.x, tid = threadIdx.x;
  const unsigned int* src = scratch + d.scr_off[bb];
  const int P = d.L[bb] >> 2;
  const int p0 = grp * PGRP;
  int cnt = 0;
  if (p0 < P) {
    const int p1 = min(p0 + PGRP, P);
    for (int p = p0 + tid; p < p1; p += 256) {
      double x1, x2, r2;
      if (polar_accept(src, p, x1, x2, r2)) cnt++;
    }
  }
  #pragma unroll
  for (int o = 32; o > 0; o >>= 1) cnt += __shfl_down(cnt, o);
  __shared__ int ws4[4];
  if ((tid & 63) == 0) ws4[tid >> 6] = cnt;
  __syncthreads();
  if (tid == 0) counts[bb * MAXG + grp] = ws4[0] + ws4[1] + ws4[2] + ws4[3];
}

__global__ void polar_scan_kernel(const int* __restrict__ counts, int* __restrict__ gbase) {
  int bb = threadIdx.x;
  if (bb < 17) {
    int acc = 0;
    for (int g = 0; g < MAXG; g++) {
      gbase[bb * MAXG + g] = acc;
      acc += counts[bb * MAXG + g];
    }
  }
}

__global__ __launch_bounds__(256)
void polar_write_kernel(const unsigned int* __restrict__ scratch, const int* __restrict__ gbase,
                        float* __restrict__ bases, GenDesc d) {
  const int bb = blockIdx.y, grp = blockIdx.x;
  const int tid = threadIdx.x;
  const int lane = tid & 63, wid = tid >> 6;
  const unsigned int* src = scratch + d.scr_off[bb];
  float* out = bases + d.basis_off[bb];
  const int n = d.n[bb];
  const int need = (n + 1) >> 1;
  const int P = d.L[bb] >> 2;
  const int p0 = grp * PGRP;
  if (p0 >= P) return;
  int base = gbase[bb * MAXG + grp];
  if (base >= need) return;
  const double sdiv = d.sdiv[bb];
  const int p1 = min(p0 + PGRP, P);
  __shared__ int lds_tot[4];
  for (int ch = p0; ch < p1 && base < need; ch += 256) {
    const int p = ch + tid;
    bool accept = false;
    double x1 = 0.0, x2 = 0.0, r2 = 0.0;
    if (p < p1) accept = polar_accept(src, p, x1, x2, r2);
    unsigned long long mask = __ballot(accept ? 1 : 0);
    int prefix = __popcll(mask & ((1ull << lane) - 1ull));
    int tot = __popcll(mask);
    if (lane == 0) lds_tot[wid] = tot;
    __syncthreads();
    int waveoff = 0;
    #pragma unroll
    for (int w = 0; w < 4; w++) waveoff += (w < wid) ? lds_tot[w] : 0;
    int tot_all = lds_tot[0] + lds_tot[1] + lds_tot[2] + lds_tot[3];
    if (accept) {
      int k = base + waveoff + prefix;
      double f = sqrt(-2.0 * log(r2) / r2);
      int i0 = 2 * k, i1 = 2 * k + 1;
      if (i0 < n) { float g = (float)(f * x2); out[i0] = (float)((double)g / sdiv); }
      if (i1 < n) { float g = (float)(f * x1); out[i1] = (float)((double)g / sdiv); }
    }
    base += tot_all;
    __syncthreads();
  }
}

// ---------------- kernel assembly: kern = einsum(w, basis), double accumulate ----------------
// writes padded layout [co][ci][49][8]
__global__ void assemble_kernel(const float* __restrict__ bases, float* __restrict__ ws, AsmDesc d) {
  int g = blockIdx.x * 256 + threadIdx.x;
  if (g >= d.cum[17]) return;
  int k = 0;
  while (g >= d.cum[k + 1]) k++;
  int l = g - d.cum[k];
  const int dd = d.dd[k], di = d.di[k], mi = d.mi[k], nb = d.nb[k];
  const int cols = mi * di;
  int tap = l % 343; int rc = l / 343;
  int c = rc % cols; int r = rc / cols;
  int o = r / dd, a = r - o * dd;
  int i = c / di, b2 = c - i * di;
  const float* wp = d.w[k];
  const float* bp = bases + d.basis_off[k] + ((a * di + b2) * 343 + tap);
  const int wbase = (o * mi + i) * nb;
  const int bstride = dd * di * 343;
  double s = 0.0;
  for (int nn = 0; nn < nb; nn++) s += (double)wp[wbase + nn] * (double)bp[(long)nn * bstride];
  int R = d.row_off[k] + r, C = d.col_off[k] + c;
  int t49 = tap / 7, kx = tap - t49 * 7;
  ws[d.koff[k] + ((long)(R * d.citot[k] + C) * 49 + t49) * 8 + kx] = (float)s;
}

// ---------------- generic direct 3D conv (stride 2, pad 3, K=7) ----------------
// Per-kz slab staging (TDZ planes, 14.8KB LDS) + CO-group split (COG channels
// per block) to cut register pressure -> higher occupancy. fp32 two-level
// accumulation (per-ci part over 343 taps -> acc; order kz,ky,c2,kx preserved).
// Weights: padded rows [49][8], wave-uniform float4 pair -> s_load_dwordx4.
// LDS row-parity swizzle breaks the even-bank stride-2 pattern.
template<int CI_TOT, int COG, int CO_TOT, int ISP, int OSP, int TDX, int TDY, int TDZ,
         int S, int CI_PER, bool ATOMIC, int SI, int CDIR>
__global__ __launch_bounds__(TDX*TDY*TDZ)
void conv3d_kernel(const float* __restrict__ src, const float* __restrict__ kern,
                   float* __restrict__ out) {
  constexpr int NT = TDX * TDY * TDZ;
  constexpr int TILE_X = TDX * S;
  constexpr int IN_X = 2 * TILE_X + 5, IN_Y = 2 * TDY + 5;
  constexpr int IN_XP = IN_X + 1;  // +1 so the parity swizzle never collides
  constexpr int SLAB = TDZ * IN_Y * IN_X;
  constexpr int NTX = OSP / TILE_X, NTY = OSP / TDY;
  constexpr int NCICH = CI_TOT / CI_PER;
  __shared__ float lds_in[TDZ * IN_Y * IN_XP + 2];
  const int tid = threadIdx.x;
  const int tx = tid % TDX, ty = (tid / TDX) % TDY, tz = tid / (TDX * TDY);
  const int bx = blockIdx.x;
  const int tXi = bx % NTX, tYi = (bx / NTX) % NTY, tZi = bx / (NTX * NTY);
  const int b = blockIdx.y;
  const int zi = blockIdx.z;
  const int cich = zi % NCICH, cog = zi / NCICH;
  const int ci0 = cich * CI_PER;
  const int co0 = cog * COG;
  const int gx0 = 2 * (tXi * TILE_X) - 3, gy0 = 2 * (tYi * TDY) - 3, gz0 = 2 * (tZi * TDZ) - 3;

  float acc[S][COG];
  #pragma unroll
  for (int u = 0; u < S; u++)
    #pragma unroll
    for (int c = 0; c < COG; c++) acc[u][c] = 0.f;

  for (int cc = 0; cc < CI_PER; cc++) {
    const int ci = ci0 + cc;
    float part[S][COG];
    #pragma unroll
    for (int u = 0; u < S; u++)
      #pragma unroll
      for (int c2 = 0; c2 < COG; c2++) part[u][c2] = 0.f;
    for (int kz = 0; kz < 7; kz++) {
      __syncthreads();  // protect previous slab's readers
      // ---- stage kz-slab: TDZ planes at gz = gz0 + 2*pz + kz ----
      for (int l = tid; l < SLAB; l += NT) {
        int dx = l % IN_X; int t2 = l / IN_X; int dy = t2 % IN_Y; int pz = t2 / IN_Y;
        int gx = gx0 + dx, gy = gy0 + dy, gz = gz0 + 2 * pz + kz;
        float v = 0.f;
        if ((unsigned)gx < (unsigned)ISP && (unsigned)gy < (unsigned)ISP &&
            (unsigned)gz < (unsigned)ISP) {
          long spi = ((long)gz * ISP + gy) * ISP + gx;
          if (ci < CDIR) {
            v = src[(long)(b * CDIR + ci) * ISP * ISP * ISP + spi];
          } else {
            int r = ci - CDIR; int vv = r / 9; int ij = r - vv * 9;
            int i2 = ij / 3, j2 = ij - i2 * 3;
            float va = src[(long)(b * CDIR + SI + 3 * vv + i2) * ISP * ISP * ISP + spi];
            float vb = src[(long)(b * CDIR + SI + 3 * vv + j2) * ISP * ISP * ISP + spi];
            v = va * vb;
          }
        }
        int r = pz * IN_Y + dy;
        lds_in[r * IN_XP + dx + ((r >> 1) & 1)] = v;
      }
      __syncthreads();
      for (int ky = 0; ky < 7; ky++) {
        const int r = tz * IN_Y + 2 * ty + ky;
        const int rowbase = r * IN_XP + ((r >> 1) & 1) + 2 * S * tx;
        float strip[2 * S + 5];
        #pragma unroll
        for (int j = 0; j < 2 * S + 5; j++) strip[j] = lds_in[rowbase + j];
        const long wrow0 = ((long)co0 * CI_TOT + ci) * 392 + (kz * 7 + ky) * 8;
        #pragma unroll
        for (int c2 = 0; c2 < COG; c2++) {
          const float* __restrict__ wrow = kern + wrow0 + (long)c2 * CI_TOT * 392;
          const float4 wa = *(const float4*)(wrow);      // wave-uniform -> s_load_dwordx4
          const float4 wb = *(const float4*)(wrow + 4);  // (slot 7 pad never consumed)
          const float wk[7] = {wa.x, wa.y, wa.z, wa.w, wb.x, wb.y, wb.z};
          #pragma unroll
          for (int kx = 0; kx < 7; kx++) {
            #pragma unroll
            for (int u = 0; u < S; u++)
              part[u][c2] += strip[2 * u + kx] * wk[kx];
          }
        }
      }
    }
    #pragma unroll
    for (int u = 0; u < S; u++)
      #pragma unroll
      for (int c2 = 0; c2 < COG; c2++) acc[u][c2] += part[u][c2];
  }
  const int ozg = tZi * TDZ + tz, oyg = tYi * TDY + ty;
  #pragma unroll
  for (int u = 0; u < S; u++) {
    const int oxg = tXi * TILE_X + tx * S + u;
    #pragma unroll
    for (int c2 = 0; c2 < COG; c2++) {
      long idx = (((long)(b * CO_TOT + co0 + c2) * OSP + ozg) * OSP + oyg) * OSP + oxg;
      if (ATOMIC) atomicAdd(&out[idx], acc[u][c2]);
      else out[idx] = acc[u][c2];
    }
  }
}

// ---------------- block-3 conv (4^3 out, 64ci expanded, 64co) ----------------
__global__ __launch_bounds__(256)
void conv_b3_kernel(const float* __restrict__ src, const float* __restrict__ k3,
                    float* __restrict__ out) {
  constexpr int CLS = 580;  // 64 rows * 9 + swizzle headroom
  __shared__ float lds_in[16 * CLS];
  const int tid = threadIdx.x;
  const int s = tid & 63, w = tid >> 6;
  const int ox = s & 3, oy = (s >> 2) & 3, oz = s >> 4;
  const int b = blockIdx.y;
  const int cogrp = blockIdx.x >> 2, cch = blockIdx.x & 3;
  const int co0 = cogrp * 16 + w * 4;
  for (int l = tid; l < 16 * 512; l += 256) {
    int cl = l >> 9, sp = l & 511;
    int ci = cch * 16 + cl;
    float v;
    if (ci < 28) v = src[(long)(b * 28 + ci) * 512 + sp];
    else {
      int r = ci - 28; int vv = r / 9; int ij = r - vv * 9;
      int i2 = ij / 3, j2 = ij - i2 * 3;
      v = src[(long)(b * 28 + 16 + 3 * vv + i2) * 512 + sp] *
          src[(long)(b * 28 + 16 + 3 * vv + j2) * 512 + sp];
    }
    int r = sp >> 3;
    lds_in[cl * CLS + r * 9 + (sp & 7) + ((r >> 1) & 1)] = v;
  }
  __syncthreads();
  float acc[4] = {0.f, 0.f, 0.f, 0.f};
  for (int cl = 0; cl < 16; cl++) {
    const int ci = cch * 16 + cl;
    float part[4] = {0.f, 0.f, 0.f, 0.f};
    for (int kz = 0; kz < 7; kz++) {
      const int iz = 2 * oz + kz - 3;
      const bool vz = (unsigned)iz < 8u;
      for (int ky = 0; ky < 7; ky++) {
        const int iy = 2 * oy + ky - 3;
        const bool vyz = vz && ((unsigned)iy < 8u);
        const int r = iz * 8 + iy;
        const int rowbase = cl * CLS + r * 9 + ((r >> 1) & 1);
        float strip[7];
        #pragma unroll
        for (int kx = 0; kx < 7; kx++) {
          const int ix = 2 * ox + kx - 3;
          strip[kx] = (vyz && (unsigned)ix < 8u) ? lds_in[rowbase + ix] : 0.f;
        }
        #pragma unroll
        for (int j = 0; j < 4; j++) {
          const float* __restrict__ wr =
              k3 + ((long)((co0 + j) * 64 + ci) * 49 + (kz * 7 + ky)) * 8;
          const float4 wa = *(const float4*)(wr);
          const float4 wb = *(const float4*)(wr + 4);
          const float wk[7] = {wa.x, wa.y, wa.z, wa.w, wb.x, wb.y, wb.z};
          #pragma unroll
          for (int kx = 0; kx < 7; kx++) part[j] += strip[kx] * wk[kx];
        }
      }
    }
    #pragma unroll
    for (int j = 0; j < 4; j++) acc[j] += part[j];
  }
  #pragma unroll
  for (int j = 0; j < 4; j++)
    atomicAdd(&out[(long)(b * 64 + co0 + j) * 64 + s], acc[j]);
}

// ---------------- reductions / norms (fp64 statistics) ----------------
__device__ inline void block_reduce2d(double& s, double& q) {
  #pragma unroll
  for (int o = 32; o > 0; o >>= 1) { s += __shfl_down(s, o); q += __shfl_down(q, o); }
  __shared__ double ls[8];
  const int lane = threadIdx.x & 63, wid = threadIdx.x >> 6;
  if (lane == 0) { ls[wid * 2] = s; ls[wid * 2 + 1] = q; }
  __syncthreads();
  if (threadIdx.x == 0) {
    for (int w = 1; w < 4; w++) { s += ls[w * 2]; q += ls[w * 2 + 1]; }
  }
}

__global__ __launch_bounds__(256)
void in_part_kernel(const float* __restrict__ x, double* __restrict__ part) {
  double s = 0.0, q = 0.0;
  const long base = (long)blockIdx.x * 4096;
  for (int i = threadIdx.x; i < 4096; i += 256) {
    double v = (double)x[base + i]; s += v; q += v * v;
  }
  block_reduce2d(s, q);
  if (threadIdx.x == 0) { part[blockIdx.x * 2] = s; part[blockIdx.x * 2 + 1] = q; }
}

__global__ __launch_bounds__(256)
void in_final_kernel(const double* __restrict__ part, double* __restrict__ st) {
  double s = 0.0, q = 0.0;
  for (int i = threadIdx.x; i < 1024; i += 256) { s += part[i * 2]; q += part[i * 2 + 1]; }
  block_reduce2d(s, q);
  if (threadIdx.x == 0) {
    const double invN = 1.0 / 4194304.0;
    double m = s * invN;
    double var = q * invN - m * m;
    st[0] = m; st[1] = 1.0 / sqrt(var + 1e-5);
  }
}

__global__ void in_apply_kernel(const float* __restrict__ x, const double* __restrict__ st,
                                float* __restrict__ xn) {
  long i = (long)blockIdx.x * 256 + threadIdx.x;
  if (i < 4194304) xn[i] = (float)(((double)x[i] - st[0]) * st[1]);
}

__global__ __launch_bounds__(256)
void stats_partial_kernel(const float* __restrict__ y, double* __restrict__ part,
                          int C, int SP, int P) {
  const int c = blockIdx.x / P, p = blockIdx.x % P;
  const int chunk = SP / P;
  double s = 0.0, q = 0.0;
  for (int b = 0; b < 16; b++) {
    const float* base = y + (long)(b * C + c) * SP + (long)p * chunk;
    for (int i = threadIdx.x; i < chunk; i += 256) {
      double v = (double)base[i]; s += v; q += v * v;
    }
  }
  block_reduce2d(s, q);
  if (threadIdx.x == 0) { part[blockIdx.x * 2] = s; part[blockIdx.x * 2 + 1] = q; }
}

__global__ __launch_bounds__(256)
void stats_final_kernel(const double* __restrict__ part, double* __restrict__ ss,
                        const float* __restrict__ g_s, const float* __restrict__ g_v,
                        const float* __restrict__ bias, int C, int P, int so, double invcount) {
  __shared__ double lsq[64];
  const int c = threadIdx.x;
  double s = 0.0, q = 0.0;
  if (c < C) {
    for (int p = 0; p < P; p++) { s += part[(c * P + p) * 2]; q += part[(c * P + p) * 2 + 1]; }
    lsq[c] = q;
  }
  __syncthreads();
  if (c < C) {
    if (c < so) {
      double m = s * invcount;
      double var = q * invcount - m * m;
      double rstd = 1.0 / sqrt(var + 1e-5);
      double sc = (double)g_s[c] * rstd;
      ss[c * 2] = sc; ss[c * 2 + 1] = (double)bias[c] - m * sc;
    } else {
      int v = (c - so) / 3;
      double n2 = (lsq[so + 3 * v] + lsq[so + 3 * v + 1] + lsq[so + 3 * v + 2]) * invcount;
      ss[c * 2] = (double)g_v[v] / sqrt(n2 + 1e-5);
      ss[c * 2 + 1] = 0.0;
    }
  }
}

__global__ void apply_kernel(float* __restrict__ y, const double* __restrict__ ss,
                             int C, int SP, int so, long total) {
  long idx = (long)blockIdx.x * 256 + threadIdx.x;
  if (idx >= total) return;
  int c = (int)((idx / SP) % C);
  double v = (double)y[idx] * ss[c * 2] + ss[c * 2 + 1];
  if (c < so) v = fmax(v, 0.0);
  y[idx] = (float)v;
}

__global__ void pool_kernel(const float* __restrict__ y3, double* __restrict__ pooled) {
  int t = blockIdx.x * 256 + threadIdx.x;
  if (t < 1024) {
    double s = 0.0;
    for (int i = 0; i < 64; i++) s += (double)y3[(long)t * 64 + i];
    pooled[t] = s * (1.0 / 64.0);
  }
}

__global__ __launch_bounds__(256)
void head_kernel(const double* __restrict__ pooled, const float* __restrict__ bn_g,
                 const float* __restrict__ bn_b, const float* __restrict__ lin_w,
                 const float* __restrict__ lin_b, float* __restrict__ out) {
  __shared__ double p[1024];
  for (int i = threadIdx.x; i < 1024; i += 256) p[i] = pooled[i];
  __syncthreads();
  if (threadIdx.x < 64) {
    int c = threadIdx.x;
    double s = 0.0, q = 0.0;
    for (int b = 0; b < 16; b++) { double v = p[b * 64 + c]; s += v; q += v * v; }
    double m = s * (1.0 / 16.0);
    double var = q * (1.0 / 16.0) - m * m;
    double rstd = 1.0 / sqrt(var + 1e-5);
    for (int b = 0; b < 16; b++)
      p[b * 64 + c] = (p[b * 64 + c] - m) * rstd * (double)bn_g[c] + (double)bn_b[c];
  }
  __syncthreads();
  if (threadIdx.x < 160) {
    int b = threadIdx.x / 10, j = threadIdx.x - b * 10;
    double s = (double)lin_b[j];
    for (int c = 0; c < 64; c++) s += p[b * 64 + c] * (double)lin_w[c * 10 + j];
    out[b * 10 + j] = (float)s;
  }
}

// ---------------- launch ----------------
extern "C" void kernel_launch(void* const* d_in, const int* in_sizes, int n_in,
                              void* d_out, int out_size, void* d_ws, size_t ws_size,
                              hipStream_t stream) {
  (void)in_sizes; (void)n_in; (void)out_size; (void)ws_size;
  float* W = (float*)d_ws;
  double* PARTD = (double*)(W + PARTD_OFF);
  double* SSD   = (double*)(W + SSD_OFF);
  double* ISTD  = (double*)(W + ISTD_OFF);
  double* POOLD = (double*)(W + POOLD_OFF);
  int* CNT   = (int*)(W + CNT_OFF);
  int* GBASE = (int*)(W + GBASE_OFF);

  // sub-block tables (k = (bi, oi, ii) in order)
  static const int k_bi[17]  = {0,0, 1,1,1,1,1,1, 2,2,2,2,2,2, 3,3,3};
  static const int k_oi[17]  = {0,1, 0,0,0,1,1,1, 0,0,0,1,1,1, 0,0,0};
  static const int k_ii[17]  = {0,0, 0,1,2,0,1,2, 0,1,2,0,1,2, 0,1,2};
  static const int k_do[17]  = {1,3, 1,1,1,3,3,3, 1,1,1,3,3,3, 1,1,1};
  static const int k_dI[17]  = {1,1, 1,3,9,1,3,9, 1,3,9,1,3,9, 1,3,9};
  static const int k_mo[17]  = {8,4, 8,8,8,4,4,4, 16,16,16,4,4,4, 64,64,64};
  static const int k_mi[17]  = {1,1, 8,4,4,8,4,4, 8,4,4,8,4,4, 16,4,4};
  static const int k_row[17] = {0,8, 0,0,0,8,8,8, 0,0,0,16,16,16, 0,0,0};
  static const int k_col[17] = {0,0, 0,8,20,0,8,20, 0,8,20,0,8,20, 0,16,28};
  static const int k_win[17] = {1,2, 6,7,8,9,10,11, 15,16,17,18,19,20, 24,25,26};
  static const int citot_by_bi[4] = {1, 56, 56, 64};
  static const long koff_by_bi[4] = {K0_OFF, K1_OFF, K2_OFF, K3_OFF};

  GenDesc gd;
  AsmDesc ad;
  int scr = 0, boff = 0, cum = 0;
  ad.cum[0] = 0;
  for (int k = 0; k < 17; k++) {
    int bi = k_bi[k];
    int dd = k_do[k], di = k_dI[k];
    int nb = 3 * (dd < di ? dd : di);
    int n = nb * dd * di * 343;
    gd.seed[k] = 1000 * bi + 10 * k_oi[k] + k_ii[k];
    gd.n[k] = n;
    int P = (3 * n) / 4 + 2048;
    gd.L[k] = 4 * P;
    gd.scr_off[k] = scr; scr += gd.L[k];
    gd.basis_off[k] = boff; boff += n;
    gd.sdiv[k] = sqrt((double)(nb * di * 343));
    ad.w[k] = (const float*)d_in[k_win[k]];
    ad.basis_off[k] = gd.basis_off[k];
    ad.row_off[k] = k_row[k]; ad.col_off[k] = k_col[k];
    ad.dd[k] = dd; ad.di[k] = di; ad.mi[k] = k_mi[k]; ad.nb[k] = nb;
    ad.citot[k] = citot_by_bi[bi];
    ad.koff[k] = koff_by_bi[bi];
    cum += k_mo[k] * dd * k_mi[k] * di * 343;
    ad.cum[k + 1] = cum;
  }

  const float* x     = (const float*)d_in[0];
  const float* g0_s  = (const float*)d_in[3];
  const float* g0_v  = (const float*)d_in[4];
  const float* bias0 = (const float*)d_in[5];
  const float* g1_s  = (const float*)d_in[12];
  const float* g1_v  = (const float*)d_in[13];
  const float* bias1 = (const float*)d_in[14];
  const float* g2_s  = (const float*)d_in[21];
  const float* g2_v  = (const float*)d_in[22];
  const float* bias2 = (const float*)d_in[23];
  const float* g3_s  = (const float*)d_in[27];
  const float* bias3 = (const float*)d_in[28];
  const float* bn_g  = (const float*)d_in[29];
  const float* bn_b  = (const float*)d_in[30];
  const float* lin_w = (const float*)d_in[31];
  const float* lin_b = (const float*)d_in[32];

  // zero atomic-accumulated conv outputs
  hipMemsetAsync(W + Y1_OFF, 0, 1310720 * 4, stream);
  hipMemsetAsync(W + Y2_OFF, 0, 229376 * 4, stream);
  hipMemsetAsync(W + Y3_OFF, 0, 65536 * 4, stream);

  // basis generation (parallel polar: count -> scan -> write) + kernel assembly
  mt_fill_kernel<<<17, 256, 0, stream>>>((unsigned int*)(W + SCR_OFF), gd);
  polar_count_kernel<<<dim3(MAXG, 17), 256, 0, stream>>>((const unsigned int*)(W + SCR_OFF),
                                                         CNT, gd);
  polar_scan_kernel<<<1, 32, 0, stream>>>(CNT, GBASE);
  polar_write_kernel<<<dim3(MAXG, 17), 256, 0, stream>>>((const unsigned int*)(W + SCR_OFF),
                                                         GBASE, W + BAS_OFF, gd);
  assemble_kernel<<<(cum + 255) / 256, 256, 0, stream>>>(W + BAS_OFF, W, ad);

  // input norm
  in_part_kernel<<<1024, 256, 0, stream>>>(x, PARTD);
  in_final_kernel<<<1, 256, 0, stream>>>(PARTD, ISTD);
  in_apply_kernel<<<16384, 256, 0, stream>>>(x, ISTD, W + XN_OFF);

  // block 0: conv 1->20ch, 64^3 -> 32^3 (co-split 2x10, slab staging)
  conv3d_kernel<1, 10, 20, 64, 32, 4, 8, 8, 2, 1, false, 0, 1>
      <<<dim3(64, 16, 2), 256, 0, stream>>>(W + XN_OFF, W + K0_OFF, W + Y0_OFF);
  stats_partial_kernel<<<20 * 32, 256, 0, stream>>>(W + Y0_OFF, PARTD, 20, 32768, 32);
  stats_final_kernel<<<1, 256, 0, stream>>>(PARTD, SSD, g0_s, g0_v, bias0,
                                            20, 32, 8, 1.0 / 524288.0);
  apply_kernel<<<40960, 256, 0, stream>>>(W + Y0_OFF, SSD, 20, 32768, 8, 10485760L);

  // block 1: conv 56->20ch, 32^3 -> 16^3 (co-split 2x10, 8 ci-chunks of 7, slab)
  conv3d_kernel<56, 10, 20, 32, 16, 4, 8, 8, 2, 7, true, 8, 20>
      <<<dim3(8, 16, 16), 256, 0, stream>>>(W + Y0_OFF, W + K1_OFF, W + Y1_OFF);
  stats_partial_kernel<<<20 * 8, 256, 0, stream>>>(W + Y1_OFF, PARTD, 20, 4096, 8);
  stats_final_kernel<<<1, 256, 0, stream>>>(PARTD, SSD, g1_s, g1_v, bias1,
                                            20, 8, 8, 1.0 / 65536.0);
  apply_kernel<<<5120, 256, 0, stream>>>(W + Y1_OFF, SSD, 20, 4096, 8, 1310720L);

  // block 2: conv 56->28ch, 16^3 -> 8^3 (whole-volume 256-thr tiles, co-split 2x14,
  // 56 ci-chunks of 1, slab)
  conv3d_kernel<56, 14, 28, 16, 8, 4, 8, 8, 2, 1, true, 8, 20>
      <<<dim3(1, 16, 112), 256, 0, stream>>>(W + Y1_OFF, W + K2_OFF, W + Y2_OFF);
  stats_partial_kernel<<<28 * 2, 256, 0, stream>>>(W + Y2_OFF, PARTD, 28, 512, 2);
  stats_final_kernel<<<1, 256, 0, stream>>>(PARTD, SSD, g2_s, g2_v, bias2,
                                            28, 2, 16, 1.0 / 8192.0);
  apply_kernel<<<896, 256, 0, stream>>>(W + Y2_OFF, SSD, 28, 512, 16, 229376L);

  // block 3: conv 64->64ch, 8^3 -> 4^3 (256 blocks, ci-chunked, atomics)
  conv_b3_kernel<<<dim3(16, 16), 256, 0, stream>>>(W + Y2_OFF, W + K3_OFF, W + Y3_OFF);
  stats_partial_kernel<<<64, 256, 0, stream>>>(W + Y3_OFF, PARTD, 64, 64, 1);
  stats_final_kernel<<<1, 256, 0, stream>>>(PARTD, SSD, g3_s, nullptr, bias3,
                                            64, 1, 64, 1.0 / 1024.0);
  apply_kernel<<<256, 256, 0, stream>>>(W + Y3_OFF, SSD, 64, 64, 64, 65536L);

  // head (fp64)
  pool_kernel<<<4, 256, 0, stream>>>(W + Y3_OFF, POOLD);
  head_kernel<<<1, 256, 0, stream>>>(POOLD, bn_g, bn_b, lin_w, lin_b, (float*)d_out);
}

// Round 11
// 1924.276 us; speedup vs baseline: 1.1154x; 1.1154x over previous
//
#include <hip/hip_runtime.h>
#include <cmath>

// ---------------- workspace layout (float offsets) ----------------
constexpr long XN_OFF   = 0;          // 16*1*64^3          = 4194304
constexpr long Y0_OFF   = 4194304;    // 16*20*32^3         = 10485760
constexpr long Y1_OFF   = 14680064;   // 16*20*16^3         = 1310720
constexpr long Y2_OFF   = 15990784;   // 16*28*8^3          = 229376
constexpr long Y3_OFF   = 16220160;   // 16*64*4^3          = 65536
// padded weight layout: [co][ci][49][8] (tap row padded 7->8 for float4 s_loads)
constexpr long K0_OFF   = 16285696;   // 20*1*392   = 7840
constexpr long K1_OFF   = 16293536;   // 20*56*392  = 439040
constexpr long K2_OFF   = 16732576;   // 28*56*392  = 614656
constexpr long K3_OFF   = 17347232;   // 64*64*392  = 1605632
constexpr long BAS_OFF  = 18952864;   // 272685 gaussians
constexpr long SCR_OFF  = 19225552;   // MT scratch (uint32), ~957k words
// double-precision regions (float offsets even for 8B alignment)
constexpr long PARTD_OFF = 20182872;  // 4096 doubles
constexpr long SSD_OFF   = 20191064;  // 128 doubles
constexpr long ISTD_OFF  = 20191320;  // 2 doubles
constexpr long POOLD_OFF = 20191324;  // 1024 doubles
constexpr long CNT_OFF   = 20193372;  // 272 ints (polar group counts)
constexpr long GBASE_OFF = 20193644;  // 272 ints (polar group bases)

constexpr int PGRP = 4096;  // candidate pairs per polar group
constexpr int MAXG = 16;    // max groups per generator

struct GenDesc {
  double sdiv[17];
  int seed[17], n[17], scr_off[17], L[17], basis_off[17];
};
struct AsmDesc {
  const float* w[17];
  int cum[18];
  int basis_off[17], row_off[17], col_off[17];
  int dd[17], di[17], mi[17], nb[17], citot[17];
  long koff[17];
};

// ---------------- MT19937 fill (parallel 3-stage twist) ----------------
__global__ __launch_bounds__(256)
void mt_fill_kernel(unsigned int* __restrict__ scratch, GenDesc d) {
  __shared__ unsigned int mt[624];
  const int bb = blockIdx.x;
  const int tid = threadIdx.x;
  if (tid == 0) {
    unsigned int s = (unsigned int)d.seed[bb];
    for (int pos = 0; pos < 624; pos++) {
      mt[pos] = s;
      s = 1812433253u * (s ^ (s >> 30)) + (unsigned)pos + 1u;
    }
  }
  __syncthreads();
  unsigned int* out = scratch + d.scr_off[bb];
  const int L = d.L[bb];
  const int ntw = (L + 623) / 624;
  for (int t = 0; t < ntw; t++) {
    unsigned int v1 = 0, v2 = 0;
    if (tid < 227) { v1 = mt[tid]; v2 = mt[tid + 1]; }
    __syncthreads();
    if (tid < 227) {
      unsigned int y = (v1 & 0x80000000u) | (v2 & 0x7fffffffu);
      mt[tid] = mt[tid + 397] ^ (y >> 1) ^ ((y & 1u) ? 0x9908b0dfu : 0u);
    }
    __syncthreads();
    if (tid < 227) { v1 = mt[227 + tid]; v2 = mt[228 + tid]; }
    __syncthreads();
    if (tid < 227) {
      unsigned int y = (v1 & 0x80000000u) | (v2 & 0x7fffffffu);
      mt[227 + tid] = mt[tid] ^ (y >> 1) ^ ((y & 1u) ? 0x9908b0dfu : 0u);
    }
    __syncthreads();
    if (tid < 170) {
      int i = 454 + tid;
      v1 = mt[i]; v2 = (i < 623) ? mt[i + 1] : mt[0];
    }
    __syncthreads();
    if (tid < 170) {
      int i = 454 + tid;
      unsigned int y = (v1 & 0x80000000u) | (v2 & 0x7fffffffu);
      mt[i] = mt[i - 227] ^ (y >> 1) ^ ((y & 1u) ? 0x9908b0dfu : 0u);
    }
    __syncthreads();
    const int base = t * 624;
    for (int j = tid; j < 624; j += 256) {
      if (base + j < L) {
        unsigned int y = mt[j];
        y ^= y >> 11;
        y ^= (y << 7) & 0x9d2c5680u;
        y ^= (y << 15) & 0xefc60000u;
        y ^= y >> 18;
        out[base + j] = y;
      }
    }
    __syncthreads();
  }
}

// ---------------- polar: count -> scan -> write (bit-exact numpy stream) ----------------
__device__ inline bool polar_accept(const unsigned int* src, int p,
                                    double& x1, double& x2, double& r2) {
  unsigned int w0 = src[4 * p], w1 = src[4 * p + 1], w2 = src[4 * p + 2], w3 = src[4 * p + 3];
  double u1 = ((double)(w0 >> 5) * 67108864.0 + (double)(w1 >> 6)) * (1.0 / 9007199254740992.0);
  double u2 = ((double)(w2 >> 5) * 67108864.0 + (double)(w3 >> 6)) * (1.0 / 9007199254740992.0);
  x1 = 2.0 * u1 - 1.0; x2 = 2.0 * u2 - 1.0;
  r2 = x1 * x1 + x2 * x2;
  return (r2 < 1.0) && (r2 != 0.0);
}

__global__ __launch_bounds__(256)
void polar_count_kernel(const unsigned int* __restrict__ scratch, int* __restrict__ counts,
                        GenDesc d) {
  const int bb = blockIdx.y, grp = blockIdx.x, tid = threadIdx.x;
  const unsigned int* src = scratch + d.scr_off[bb];
  const int P = d.L[bb] >> 2;
  const int p0 = grp * PGRP;
  int cnt = 0;
  if (p0 < P) {
    const int p1 = min(p0 + PGRP, P);
    for (int p = p0 + tid; p < p1; p += 256) {
      double x1, x2, r2;
      if (polar_accept(src, p, x1, x2, r2)) cnt++;
    }
  }
  #pragma unroll
  for (int o = 32; o > 0; o >>= 1) cnt += __shfl_down(cnt, o);
  __shared__ int ws4[4];
  if ((tid & 63) == 0) ws4[tid >> 6] = cnt;
  __syncthreads();
  if (tid == 0) counts[bb * MAXG + grp] = ws4[0] + ws4[1] + ws4[2] + ws4[3];
}

__global__ void polar_scan_kernel(const int* __restrict__ counts, int* __restrict__ gbase) {
  int bb = threadIdx.x;
  if (bb < 17) {
    int acc = 0;
    for (int g = 0; g < MAXG; g++) {
      gbase[bb * MAXG + g] = acc;
      acc += counts[bb * MAXG + g];
    }
  }
}

__global__ __launch_bounds__(256)
void polar_write_kernel(const unsigned int* __restrict__ scratch, const int* __restrict__ gbase,
                        float* __restrict__ bases, GenDesc d) {
  const int bb = blockIdx.y, grp = blockIdx.x;
  const int tid = threadIdx.x;
  const int lane = tid & 63, wid = tid >> 6;
  const unsigned int* src = scratch + d.scr_off[bb];
  float* out = bases + d.basis_off[bb];
  const int n = d.n[bb];
  const int need = (n + 1) >> 1;
  const int P = d.L[bb] >> 2;
  const int p0 = grp * PGRP;
  if (p0 >= P) return;
  int base = gbase[bb * MAXG + grp];
  if (base >= need) return;
  const double sdiv = d.sdiv[bb];
  const int p1 = min(p0 + PGRP, P);
  __shared__ int lds_tot[4];
  for (int ch = p0; ch < p1 && base < need; ch += 256) {
    const int p = ch + tid;
    bool accept = false;
    double x1 = 0.0, x2 = 0.0, r2 = 0.0;
    if (p < p1) accept = polar_accept(src, p, x1, x2, r2);
    unsigned long long mask = __ballot(accept ? 1 : 0);
    int prefix = __popcll(mask & ((1ull << lane) - 1ull));
    int tot = __popcll(mask);
    if (lane == 0) lds_tot[wid] = tot;
    __syncthreads();
    int waveoff = 0;
    #pragma unroll
    for (int w = 0; w < 4; w++) waveoff += (w < wid) ? lds_tot[w] : 0;
    int tot_all = lds_tot[0] + lds_tot[1] + lds_tot[2] + lds_tot[3];
    if (accept) {
      int k = base + waveoff + prefix;
      double f = sqrt(-2.0 * log(r2) / r2);
      int i0 = 2 * k, i1 = 2 * k + 1;
      if (i0 < n) { float g = (float)(f * x2); out[i0] = (float)((double)g / sdiv); }
      if (i1 < n) { float g = (float)(f * x1); out[i1] = (float)((double)g / sdiv); }
    }
    base += tot_all;
    __syncthreads();
  }
}

// ---------------- kernel assembly: kern = einsum(w, basis), double accumulate ----------------
// writes padded layout [co][ci][49][8]
__global__ void assemble_kernel(const float* __restrict__ bases, float* __restrict__ ws, AsmDesc d) {
  int g = blockIdx.x * 256 + threadIdx.x;
  if (g >= d.cum[17]) return;
  int k = 0;
  while (g >= d.cum[k + 1]) k++;
  int l = g - d.cum[k];
  const int dd = d.dd[k], di = d.di[k], mi = d.mi[k], nb = d.nb[k];
  const int cols = mi * di;
  int tap = l % 343; int rc = l / 343;
  int c = rc % cols; int r = rc / cols;
  int o = r / dd, a = r - o * dd;
  int i = c / di, b2 = c - i * di;
  const float* wp = d.w[k];
  const float* bp = bases + d.basis_off[k] + ((a * di + b2) * 343 + tap);
  const int wbase = (o * mi + i) * nb;
  const int bstride = dd * di * 343;
  double s = 0.0;
  for (int nn = 0; nn < nb; nn++) s += (double)wp[wbase + nn] * (double)bp[(long)nn * bstride];
  int R = d.row_off[k] + r, C = d.col_off[k] + c;
  int t49 = tap / 7, kx = tap - t49 * 7;
  ws[d.koff[k] + ((long)(R * d.citot[k] + C) * 49 + t49) * 8 + kx] = (float)s;
}

// ---------------- generic direct 3D conv (stride 2, pad 3, K=7) ----------------
// CO-group split (COG channels per block) for register relief. Two staging
// modes: SLAB=true stages per-kz z-slabs (14.8KB LDS, for staging-light
// blocks); SLAB=false stages the full input tile once per ci (38.8KB LDS,
// for staging-heavy blocks -- min redundancy, 2 barriers per ci).
// fp32 two-level accumulation (per-ci part over 343 taps -> acc; order
// kz,ky,c2,kx preserved). Weights: padded rows [49][8], wave-uniform float4
// pair -> s_load_dwordx4. LDS row-parity swizzle breaks even-bank stride-2.
template<int CI_TOT, int COG, int CO_TOT, int ISP, int OSP, int TDX, int TDY, int TDZ,
         int S, int CI_PER, bool ATOMIC, bool SLAB, int SI, int CDIR>
__global__ __launch_bounds__(TDX*TDY*TDZ)
void conv3d_kernel(const float* __restrict__ src, const float* __restrict__ kern,
                   float* __restrict__ out) {
  constexpr int NT = TDX * TDY * TDZ;
  constexpr int TILE_X = TDX * S;
  constexpr int IN_X = 2 * TILE_X + 5, IN_Y = 2 * TDY + 5, IN_Z = 2 * TDZ + 5;
  constexpr int IN_XP = IN_X + 1;  // +1 so the parity swizzle never collides
  constexpr int SLABSZ = TDZ * IN_Y * IN_X;
  constexpr int FULLSZ = IN_Z * IN_Y * IN_X;
  constexpr int NTX = OSP / TILE_X, NTY = OSP / TDY;
  constexpr int NCICH = CI_TOT / CI_PER;
  constexpr int LDSZ = (SLAB ? TDZ : IN_Z) * IN_Y * IN_XP + 2;
  __shared__ float lds_in[LDSZ];
  const int tid = threadIdx.x;
  const int tx = tid % TDX, ty = (tid / TDX) % TDY, tz = tid / (TDX * TDY);
  const int bx = blockIdx.x;
  const int tXi = bx % NTX, tYi = (bx / NTX) % NTY, tZi = bx / (NTX * NTY);
  const int b = blockIdx.y;
  const int zi = blockIdx.z;
  const int cich = zi % NCICH, cog = zi / NCICH;
  const int ci0 = cich * CI_PER;
  const int co0 = cog * COG;
  const int gx0 = 2 * (tXi * TILE_X) - 3, gy0 = 2 * (tYi * TDY) - 3, gz0 = 2 * (tZi * TDZ) - 3;

  float acc[S][COG];
  #pragma unroll
  for (int u = 0; u < S; u++)
    #pragma unroll
    for (int c = 0; c < COG; c++) acc[u][c] = 0.f;

  for (int cc = 0; cc < CI_PER; cc++) {
    const int ci = ci0 + cc;
    if constexpr (!SLAB) {
      // ---- stage full input tile once per ci ----
      for (int l = tid; l < FULLSZ; l += NT) {
        int dx = l % IN_X; int t2 = l / IN_X; int dy = t2 % IN_Y; int dz = t2 / IN_Y;
        int gx = gx0 + dx, gy = gy0 + dy, gz = gz0 + dz;
        float v = 0.f;
        if ((unsigned)gx < (unsigned)ISP && (unsigned)gy < (unsigned)ISP &&
            (unsigned)gz < (unsigned)ISP) {
          long spi = ((long)gz * ISP + gy) * ISP + gx;
          if (ci < CDIR) {
            v = src[(long)(b * CDIR + ci) * ISP * ISP * ISP + spi];
          } else {
            int r = ci - CDIR; int vv = r / 9; int ij = r - vv * 9;
            int i2 = ij / 3, j2 = ij - i2 * 3;
            float va = src[(long)(b * CDIR + SI + 3 * vv + i2) * ISP * ISP * ISP + spi];
            float vb = src[(long)(b * CDIR + SI + 3 * vv + j2) * ISP * ISP * ISP + spi];
            v = va * vb;
          }
        }
        int r = dz * IN_Y + dy;
        lds_in[r * IN_XP + dx + ((r >> 1) & 1)] = v;
      }
      __syncthreads();
    }
    float part[S][COG];
    #pragma unroll
    for (int u = 0; u < S; u++)
      #pragma unroll
      for (int c2 = 0; c2 < COG; c2++) part[u][c2] = 0.f;
    for (int kz = 0; kz < 7; kz++) {
      if constexpr (SLAB) {
        __syncthreads();  // protect previous slab's readers
        // ---- stage kz-slab: TDZ planes at gz = gz0 + 2*pz + kz ----
        for (int l = tid; l < SLABSZ; l += NT) {
          int dx = l % IN_X; int t2 = l / IN_X; int dy = t2 % IN_Y; int pz = t2 / IN_Y;
          int gx = gx0 + dx, gy = gy0 + dy, gz = gz0 + 2 * pz + kz;
          float v = 0.f;
          if ((unsigned)gx < (unsigned)ISP && (unsigned)gy < (unsigned)ISP &&
              (unsigned)gz < (unsigned)ISP) {
            long spi = ((long)gz * ISP + gy) * ISP + gx;
            if (ci < CDIR) {
              v = src[(long)(b * CDIR + ci) * ISP * ISP * ISP + spi];
            } else {
              int r = ci - CDIR; int vv = r / 9; int ij = r - vv * 9;
              int i2 = ij / 3, j2 = ij - i2 * 3;
              float va = src[(long)(b * CDIR + SI + 3 * vv + i2) * ISP * ISP * ISP + spi];
              float vb = src[(long)(b * CDIR + SI + 3 * vv + j2) * ISP * ISP * ISP + spi];
              v = va * vb;
            }
          }
          int r = pz * IN_Y + dy;
          lds_in[r * IN_XP + dx + ((r >> 1) & 1)] = v;
        }
        __syncthreads();
      }
      for (int ky = 0; ky < 7; ky++) {
        const int r = SLAB ? (tz * IN_Y + 2 * ty + ky)
                           : ((2 * tz + kz) * IN_Y + 2 * ty + ky);
        const int rowbase = r * IN_XP + ((r >> 1) & 1) + 2 * S * tx;
        float strip[2 * S + 5];
        #pragma unroll
        for (int j = 0; j < 2 * S + 5; j++) strip[j] = lds_in[rowbase + j];
        const long wrow0 = ((long)co0 * CI_TOT + ci) * 392 + (kz * 7 + ky) * 8;
        #pragma unroll
        for (int c2 = 0; c2 < COG; c2++) {
          const float* __restrict__ wrow = kern + wrow0 + (long)c2 * CI_TOT * 392;
          const float4 wa = *(const float4*)(wrow);      // wave-uniform -> s_load_dwordx4
          const float4 wb = *(const float4*)(wrow + 4);  // (slot 7 pad never consumed)
          const float wk[7] = {wa.x, wa.y, wa.z, wa.w, wb.x, wb.y, wb.z};
          #pragma unroll
          for (int kx = 0; kx < 7; kx++) {
            #pragma unroll
            for (int u = 0; u < S; u++)
              part[u][c2] += strip[2 * u + kx] * wk[kx];
          }
        }
      }
    }
    #pragma unroll
    for (int u = 0; u < S; u++)
      #pragma unroll
      for (int c2 = 0; c2 < COG; c2++) acc[u][c2] += part[u][c2];
    if constexpr (!SLAB) __syncthreads();  // before next ci restages
  }
  const int ozg = tZi * TDZ + tz, oyg = tYi * TDY + ty;
  #pragma unroll
  for (int u = 0; u < S; u++) {
    const int oxg = tXi * TILE_X + tx * S + u;
    #pragma unroll
    for (int c2 = 0; c2 < COG; c2++) {
      long idx = (((long)(b * CO_TOT + co0 + c2) * OSP + ozg) * OSP + oyg) * OSP + oxg;
      if (ATOMIC) atomicAdd(&out[idx], acc[u][c2]);
      else out[idx] = acc[u][c2];
    }
  }
}

// ---------------- block-3 conv (4^3 out, 64ci expanded, 64co) ----------------
__global__ __launch_bounds__(256)
void conv_b3_kernel(const float* __restrict__ src, const float* __restrict__ k3,
                    float* __restrict__ out) {
  constexpr int CLS = 580;  // 64 rows * 9 + swizzle headroom
  __shared__ float lds_in[16 * CLS];
  const int tid = threadIdx.x;
  const int s = tid & 63, w = tid >> 6;
  const int ox = s & 3, oy = (s >> 2) & 3, oz = s >> 4;
  const int b = blockIdx.y;
  const int cogrp = blockIdx.x >> 2, cch = blockIdx.x & 3;
  const int co0 = cogrp * 16 + w * 4;
  for (int l = tid; l < 16 * 512; l += 256) {
    int cl = l >> 9, sp = l & 511;
    int ci = cch * 16 + cl;
    float v;
    if (ci < 28) v = src[(long)(b * 28 + ci) * 512 + sp];
    else {
      int r = ci - 28; int vv = r / 9; int ij = r - vv * 9;
      int i2 = ij / 3, j2 = ij - i2 * 3;
      v = src[(long)(b * 28 + 16 + 3 * vv + i2) * 512 + sp] *
          src[(long)(b * 28 + 16 + 3 * vv + j2) * 512 + sp];
    }
    int r = sp >> 3;
    lds_in[cl * CLS + r * 9 + (sp & 7) + ((r >> 1) & 1)] = v;
  }
  __syncthreads();
  float acc[4] = {0.f, 0.f, 0.f, 0.f};
  for (int cl = 0; cl < 16; cl++) {
    const int ci = cch * 16 + cl;
    float part[4] = {0.f, 0.f, 0.f, 0.f};
    for (int kz = 0; kz < 7; kz++) {
      const int iz = 2 * oz + kz - 3;
      const bool vz = (unsigned)iz < 8u;
      for (int ky = 0; ky < 7; ky++) {
        const int iy = 2 * oy + ky - 3;
        const bool vyz = vz && ((unsigned)iy < 8u);
        const int r = iz * 8 + iy;
        const int rowbase = cl * CLS + r * 9 + ((r >> 1) & 1);
        float strip[7];
        #pragma unroll
        for (int kx = 0; kx < 7; kx++) {
          const int ix = 2 * ox + kx - 3;
          strip[kx] = (vyz && (unsigned)ix < 8u) ? lds_in[rowbase + ix] : 0.f;
        }
        #pragma unroll
        for (int j = 0; j < 4; j++) {
          const float* __restrict__ wr =
              k3 + ((long)((co0 + j) * 64 + ci) * 49 + (kz * 7 + ky)) * 8;
          const float4 wa = *(const float4*)(wr);
          const float4 wb = *(const float4*)(wr + 4);
          const float wk[7] = {wa.x, wa.y, wa.z, wa.w, wb.x, wb.y, wb.z};
          #pragma unroll
          for (int kx = 0; kx < 7; kx++) part[j] += strip[kx] * wk[kx];
        }
      }
    }
    #pragma unroll
    for (int j = 0; j < 4; j++) acc[j] += part[j];
  }
  #pragma unroll
  for (int j = 0; j < 4; j++)
    atomicAdd(&out[(long)(b * 64 + co0 + j) * 64 + s], acc[j]);
}

// ---------------- reductions / norms (fp64 statistics) ----------------
__device__ inline void block_reduce2d(double& s, double& q) {
  #pragma unroll
  for (int o = 32; o > 0; o >>= 1) { s += __shfl_down(s, o); q += __shfl_down(q, o); }
  __shared__ double ls[8];
  const int lane = threadIdx.x & 63, wid = threadIdx.x >> 6;
  if (lane == 0) { ls[wid * 2] = s; ls[wid * 2 + 1] = q; }
  __syncthreads();
  if (threadIdx.x == 0) {
    for (int w = 1; w < 4; w++) { s += ls[w * 2]; q += ls[w * 2 + 1]; }
  }
}

__global__ __launch_bounds__(256)
void in_part_kernel(const float* __restrict__ x, double* __restrict__ part) {
  double s = 0.0, q = 0.0;
  const long base = (long)blockIdx.x * 4096;
  for (int i = threadIdx.x; i < 4096; i += 256) {
    double v = (double)x[base + i]; s += v; q += v * v;
  }
  block_reduce2d(s, q);
  if (threadIdx.x == 0) { part[blockIdx.x * 2] = s; part[blockIdx.x * 2 + 1] = q; }
}

__global__ __launch_bounds__(256)
void in_final_kernel(const double* __restrict__ part, double* __restrict__ st) {
  double s = 0.0, q = 0.0;
  for (int i = threadIdx.x; i < 1024; i += 256) { s += part[i * 2]; q += part[i * 2 + 1]; }
  block_reduce2d(s, q);
  if (threadIdx.x == 0) {
    const double invN = 1.0 / 4194304.0;
    double m = s * invN;
    double var = q * invN - m * m;
    st[0] = m; st[1] = 1.0 / sqrt(var + 1e-5);
  }
}

__global__ void in_apply_kernel(const float* __restrict__ x, const double* __restrict__ st,
                                float* __restrict__ xn) {
  long i = (long)blockIdx.x * 256 + threadIdx.x;
  if (i < 4194304) xn[i] = (float)(((double)x[i] - st[0]) * st[1]);
}

__global__ __launch_bounds__(256)
void stats_partial_kernel(const float* __restrict__ y, double* __restrict__ part,
                          int C, int SP, int P) {
  const int c = blockIdx.x / P, p = blockIdx.x % P;
  const int chunk = SP / P;
  double s = 0.0, q = 0.0;
  for (int b = 0; b < 16; b++) {
    const float* base = y + (long)(b * C + c) * SP + (long)p * chunk;
    for (int i = threadIdx.x; i < chunk; i += 256) {
      double v = (double)base[i]; s += v; q += v * v;
    }
  }
  block_reduce2d(s, q);
  if (threadIdx.x == 0) { part[blockIdx.x * 2] = s; part[blockIdx.x * 2 + 1] = q; }
}

__global__ __launch_bounds__(256)
void stats_final_kernel(const double* __restrict__ part, double* __restrict__ ss,
                        const float* __restrict__ g_s, const float* __restrict__ g_v,
                        const float* __restrict__ bias, int C, int P, int so, double invcount) {
  __shared__ double lsq[64];
  const int c = threadIdx.x;
  double s = 0.0, q = 0.0;
  if (c < C) {
    for (int p = 0; p < P; p++) { s += part[(c * P + p) * 2]; q += part[(c * P + p) * 2 + 1]; }
    lsq[c] = q;
  }
  __syncthreads();
  if (c < C) {
    if (c < so) {
      double m = s * invcount;
      double var = q * invcount - m * m;
      double rstd = 1.0 / sqrt(var + 1e-5);
      double sc = (double)g_s[c] * rstd;
      ss[c * 2] = sc; ss[c * 2 + 1] = (double)bias[c] - m * sc;
    } else {
      int v = (c - so) / 3;
      double n2 = (lsq[so + 3 * v] + lsq[so + 3 * v + 1] + lsq[so + 3 * v + 2]) * invcount;
      ss[c * 2] = (double)g_v[v] / sqrt(n2 + 1e-5);
      ss[c * 2 + 1] = 0.0;
    }
  }
}

__global__ void apply_kernel(float* __restrict__ y, const double* __restrict__ ss,
                             int C, int SP, int so, long total) {
  long idx = (long)blockIdx.x * 256 + threadIdx.x;
  if (idx >= total) return;
  int c = (int)((idx / SP) % C);
  double v = (double)y[idx] * ss[c * 2] + ss[c * 2 + 1];
  if (c < so) v = fmax(v, 0.0);
  y[idx] = (float)v;
}

__global__ void pool_kernel(const float* __restrict__ y3, double* __restrict__ pooled) {
  int t = blockIdx.x * 256 + threadIdx.x;
  if (t < 1024) {
    double s = 0.0;
    for (int i = 0; i < 64; i++) s += (double)y3[(long)t * 64 + i];
    pooled[t] = s * (1.0 / 64.0);
  }
}

__global__ __launch_bounds__(256)
void head_kernel(const double* __restrict__ pooled, const float* __restrict__ bn_g,
                 const float* __restrict__ bn_b, const float* __restrict__ lin_w,
                 const float* __restrict__ lin_b, float* __restrict__ out) {
  __shared__ double p[1024];
  for (int i = threadIdx.x; i < 1024; i += 256) p[i] = pooled[i];
  __syncthreads();
  if (threadIdx.x < 64) {
    int c = threadIdx.x;
    double s = 0.0, q = 0.0;
    for (int b = 0; b < 16; b++) { double v = p[b * 64 + c]; s += v; q += v * v; }
    double m = s * (1.0 / 16.0);
    double var = q * (1.0 / 16.0) - m * m;
    double rstd = 1.0 / sqrt(var + 1e-5);
    for (int b = 0; b < 16; b++)
      p[b * 64 + c] = (p[b * 64 + c] - m) * rstd * (double)bn_g[c] + (double)bn_b[c];
  }
  __syncthreads();
  if (threadIdx.x < 160) {
    int b = threadIdx.x / 10, j = threadIdx.x - b * 10;
    double s = (double)lin_b[j];
    for (int c = 0; c < 64; c++) s += p[b * 64 + c] * (double)lin_w[c * 10 + j];
    out[b * 10 + j] = (float)s;
  }
}

// ---------------- launch ----------------
extern "C" void kernel_launch(void* const* d_in, const int* in_sizes, int n_in,
                              void* d_out, int out_size, void* d_ws, size_t ws_size,
                              hipStream_t stream) {
  (void)in_sizes; (void)n_in; (void)out_size; (void)ws_size;
  float* W = (float*)d_ws;
  double* PARTD = (double*)(W + PARTD_OFF);
  double* SSD   = (double*)(W + SSD_OFF);
  double* ISTD  = (double*)(W + ISTD_OFF);
  double* POOLD = (double*)(W + POOLD_OFF);
  int* CNT   = (int*)(W + CNT_OFF);
  int* GBASE = (int*)(W + GBASE_OFF);

  // sub-block tables (k = (bi, oi, ii) in order)
  static const int k_bi[17]  = {0,0, 1,1,1,1,1,1, 2,2,2,2,2,2, 3,3,3};
  static const int k_oi[17]  = {0,1, 0,0,0,1,1,1, 0,0,0,1,1,1, 0,0,0};
  static const int k_ii[17]  = {0,0, 0,1,2,0,1,2, 0,1,2,0,1,2, 0,1,2};
  static const int k_do[17]  = {1,3, 1,1,1,3,3,3, 1,1,1,3,3,3, 1,1,1};
  static const int k_dI[17]  = {1,1, 1,3,9,1,3,9, 1,3,9,1,3,9, 1,3,9};
  static const int k_mo[17]  = {8,4, 8,8,8,4,4,4, 16,16,16,4,4,4, 64,64,64};
  static const int k_mi[17]  = {1,1, 8,4,4,8,4,4, 8,4,4,8,4,4, 16,4,4};
  static const int k_row[17] = {0,8, 0,0,0,8,8,8, 0,0,0,16,16,16, 0,0,0};
  static const int k_col[17] = {0,0, 0,8,20,0,8,20, 0,8,20,0,8,20, 0,16,28};
  static const int k_win[17] = {1,2, 6,7,8,9,10,11, 15,16,17,18,19,20, 24,25,26};
  static const int citot_by_bi[4] = {1, 56, 56, 64};
  static const long koff_by_bi[4] = {K0_OFF, K1_OFF, K2_OFF, K3_OFF};

  GenDesc gd;
  AsmDesc ad;
  int scr = 0, boff = 0, cum = 0;
  ad.cum[0] = 0;
  for (int k = 0; k < 17; k++) {
    int bi = k_bi[k];
    int dd = k_do[k], di = k_dI[k];
    int nb = 3 * (dd < di ? dd : di);
    int n = nb * dd * di * 343;
    gd.seed[k] = 1000 * bi + 10 * k_oi[k] + k_ii[k];
    gd.n[k] = n;
    int P = (3 * n) / 4 + 2048;
    gd.L[k] = 4 * P;
    gd.scr_off[k] = scr; scr += gd.L[k];
    gd.basis_off[k] = boff; boff += n;
    gd.sdiv[k] = sqrt((double)(nb * di * 343));
    ad.w[k] = (const float*)d_in[k_win[k]];
    ad.basis_off[k] = gd.basis_off[k];
    ad.row_off[k] = k_row[k]; ad.col_off[k] = k_col[k];
    ad.dd[k] = dd; ad.di[k] = di; ad.mi[k] = k_mi[k]; ad.nb[k] = nb;
    ad.citot[k] = citot_by_bi[bi];
    ad.koff[k] = koff_by_bi[bi];
    cum += k_mo[k] * dd * k_mi[k] * di * 343;
    ad.cum[k + 1] = cum;
  }

  const float* x     = (const float*)d_in[0];
  const float* g0_s  = (const float*)d_in[3];
  const float* g0_v  = (const float*)d_in[4];
  const float* bias0 = (const float*)d_in[5];
  const float* g1_s  = (const float*)d_in[12];
  const float* g1_v  = (const float*)d_in[13];
  const float* bias1 = (const float*)d_in[14];
  const float* g2_s  = (const float*)d_in[21];
  const float* g2_v  = (const float*)d_in[22];
  const float* bias2 = (const float*)d_in[23];
  const float* g3_s  = (const float*)d_in[27];
  const float* bias3 = (const float*)d_in[28];
  const float* bn_g  = (const float*)d_in[29];
  const float* bn_b  = (const float*)d_in[30];
  const float* lin_w = (const float*)d_in[31];
  const float* lin_b = (const float*)d_in[32];

  // zero atomic-accumulated conv outputs
  hipMemsetAsync(W + Y1_OFF, 0, 1310720 * 4, stream);
  hipMemsetAsync(W + Y2_OFF, 0, 229376 * 4, stream);
  hipMemsetAsync(W + Y3_OFF, 0, 65536 * 4, stream);

  // basis generation (parallel polar: count -> scan -> write) + kernel assembly
  mt_fill_kernel<<<17, 256, 0, stream>>>((unsigned int*)(W + SCR_OFF), gd);
  polar_count_kernel<<<dim3(MAXG, 17), 256, 0, stream>>>((const unsigned int*)(W + SCR_OFF),
                                                         CNT, gd);
  polar_scan_kernel<<<1, 32, 0, stream>>>(CNT, GBASE);
  polar_write_kernel<<<dim3(MAXG, 17), 256, 0, stream>>>((const unsigned int*)(W + SCR_OFF),
                                                         GBASE, W + BAS_OFF, gd);
  assemble_kernel<<<(cum + 255) / 256, 256, 0, stream>>>(W + BAS_OFF, W, ad);

  // input norm
  in_part_kernel<<<1024, 256, 0, stream>>>(x, PARTD);
  in_final_kernel<<<1, 256, 0, stream>>>(PARTD, ISTD);
  in_apply_kernel<<<16384, 256, 0, stream>>>(x, ISTD, W + XN_OFF);

  // block 0: conv 1->20ch, 64^3 -> 32^3 (co-split 2x10, slab staging)
  conv3d_kernel<1, 10, 20, 64, 32, 4, 8, 8, 2, 1, false, true, 0, 1>
      <<<dim3(64, 16, 2), 256, 0, stream>>>(W + XN_OFF, W + K0_OFF, W + Y0_OFF);
  stats_partial_kernel<<<20 * 32, 256, 0, stream>>>(W + Y0_OFF, PARTD, 20, 32768, 32);
  stats_final_kernel<<<1, 256, 0, stream>>>(PARTD, SSD, g0_s, g0_v, bias0,
                                            20, 32, 8, 1.0 / 524288.0);
  apply_kernel<<<40960, 256, 0, stream>>>(W + Y0_OFF, SSD, 20, 32768, 8, 10485760L);

  // block 1: conv 56->20ch, 32^3 -> 16^3 (co-split 2x10, FULL-TILE staging,
  // 8 ci-chunks of 7; staging-heavy -> minimize staged elements)
  conv3d_kernel<56, 10, 20, 32, 16, 4, 8, 8, 2, 7, true, false, 8, 20>
      <<<dim3(8, 16, 16), 256, 0, stream>>>(W + Y0_OFF, W + K1_OFF, W + Y1_OFF);
  stats_partial_kernel<<<20 * 8, 256, 0, stream>>>(W + Y1_OFF, PARTD, 20, 4096, 8);
  stats_final_kernel<<<1, 256, 0, stream>>>(PARTD, SSD, g1_s, g1_v, bias1,
                                            20, 8, 8, 1.0 / 65536.0);
  apply_kernel<<<5120, 256, 0, stream>>>(W + Y1_OFF, SSD, 20, 4096, 8, 1310720L);

  // block 2: conv 56->28ch, 16^3 -> 8^3 (whole-volume 256-thr tiles, co-split 2x14,
  // 56 ci-chunks of 1, slab)
  conv3d_kernel<56, 14, 28, 16, 8, 4, 8, 8, 2, 1, true, true, 8, 20>
      <<<dim3(1, 16, 112), 256, 0, stream>>>(W + Y1_OFF, W + K2_OFF, W + Y2_OFF);
  stats_partial_kernel<<<28 * 2, 256, 0, stream>>>(W + Y2_OFF, PARTD, 28, 512, 2);
  stats_final_kernel<<<1, 256, 0, stream>>>(PARTD, SSD, g2_s, g2_v, bias2,
                                            28, 2, 16, 1.0 / 8192.0);
  apply_kernel<<<896, 256, 0, stream>>>(W + Y2_OFF, SSD, 28, 512, 16, 229376L);

  // block 3: conv 64->64ch, 8^3 -> 4^3 (256 blocks, ci-chunked, atomics)
  conv_b3_kernel<<<dim3(16, 16), 256, 0, stream>>>(W + Y2_OFF, W + K3_OFF, W + Y3_OFF);
  stats_partial_kernel<<<64, 256, 0, stream>>>(W + Y3_OFF, PARTD, 64, 64, 1);
  stats_final_kernel<<<1, 256, 0, stream>>>(PARTD, SSD, g3_s, nullptr, bias3,
                                            64, 1, 64, 1.0 / 1024.0);
  apply_kernel<<<256, 256, 0, stream>>>(W + Y3_OFF, SSD, 64, 64, 64, 65536L);

  // head (fp64)
  pool_kernel<<<4, 256, 0, stream>>>(W + Y3_OFF, POOLD);
  head_kernel<<<1, 256, 0, stream>>>(POOLD, bn_g, bn_b, lin_w, lin_b, (float*)d_out);
}